// Round 1
// baseline (544.254 us; speedup 1.0000x reference)
//
#include <hip/hip_runtime.h>
#include <hip/hip_bf16.h>

#define BS_   2048
#define HID_  512
#define PH_   32

typedef _Float16 half8 __attribute__((ext_vector_type(8)));
typedef float floatx4 __attribute__((ext_vector_type(4)));

__device__ __forceinline__ float sigf(float x) { return 1.f / (1.f + __expf(-x)); }
__device__ __forceinline__ float tanhfast(float x) {
    float e = __expf(2.f * x);          // e=inf -> 1, e->0 -> -1 : safe at extremes
    return 1.f - 2.f / (e + 1.f);
}

// ---------------------------------------------------------------------------
// Prep: fp32 -> fp16 weights, combined weight W_ih+W_hh, combined bias, z16.
// ---------------------------------------------------------------------------
__global__ __launch_bounds__(256) void prep_kernel(
    const float* __restrict__ Wih, const float* __restrict__ Whh,
    const float* __restrict__ bih, const float* __restrict__ bhh,
    const float* __restrict__ z,
    _Float16* __restrict__ wih16, _Float16* __restrict__ wsum16,
    _Float16* __restrict__ z16, float* __restrict__ bsum)
{
    int i = blockIdx.x * 256 + threadIdx.x;          // [0, 1048576)
    if (i < BS_ * HID_) z16[i] = (_Float16)z[i];
    if (i < 4 * HID_ * HID_) {
        float a = Wih[i];
        wih16[i]  = (_Float16)a;
        wsum16[i] = (_Float16)(a + Whh[i]);
    }
    if (i < 4 * HID_) bsum[i] = bih[i] + bhh[i];
}

// ---------------------------------------------------------------------------
// One LSTM step. Grid = 256 blocks: blockIdx = ib*32 + j
//   ib in [0,8): batch tile of 256 rows
//   j  in [0,32): hidden slice of 16 units -> 64 gate rows (i,f,g,o x 16)
// Block tile: [256 M, 64 N], K = 512. 4 waves, each 4M x 4N of 16x16x32 f16.
// N-tile g == gate g, so each thread holds i,f,g,o for the same (row, hid).
// Weight slice lives in exactly 64 KB LDS, XOR-swizzled on 16B blocks so the
// B-fragment ds_read_b128 is only 2-way bank-aliased (free).
// ---------------------------------------------------------------------------
__global__ __launch_bounds__(256) void lstm_step_kernel(
    const _Float16* __restrict__ Wg,    // [2048,512] fp16 (wih16 for t==0 else wsum16)
    const float* __restrict__ bsum,     // [2048]
    const _Float16* __restrict__ x_in,  // [2048,512] fp16 (z16 or hs[t-1])
    _Float16* __restrict__ h_out,       // hs[t]
    float* __restrict__ c_ws,           // persistent cell state, thread-ownership order
    int t)
{
    __shared__ _Float16 Wl[64 * 512];   // 64 KB

    const int tid  = threadIdx.x;
    const int j    = blockIdx.x & 31;
    const int ib   = blockIdx.x >> 5;
    const int lane = tid & 63;
    const int wv   = tid >> 6;          // wave 0..3 -> M strip of 64 rows
    const int qw   = lane >> 4;         // quad 0..3
    const int ln   = lane & 15;

    // ---- stage weight slice into LDS (xor swizzle on 16B blocks) ----
    for (int rep = 0; rep < 16; ++rep) {
        int idx = rep * 256 + tid;      // [0, 4096) over (row n, 16B-block kb)
        int n  = idx >> 6;
        int kb = idx & 63;
        int g  = n >> 4, u = n & 15;
        const half8* src = (const half8*)(Wg + ((size_t)(g * HID_ + j * 16 + u)) * HID_ + kb * 8);
        int phys = (kb & 56) | ((kb & 7) ^ (n & 7));
        *(half8*)((char*)Wl + n * 1024 + phys * 16) = *src;
    }
    __syncthreads();

    const int hid = j * 16 + ln;
    float bias[4];
#pragma unroll
    for (int g = 0; g < 4; ++g) bias[g] = bsum[g * HID_ + hid];

    // ---- cell state: registers, spilled to ws between launches ----
    float c[4][4];
    float* cbase = c_ws + (size_t)blockIdx.x * 4096 + wv * 1024 + lane;
    if (t == 0) {
#pragma unroll
        for (int mt = 0; mt < 4; ++mt)
#pragma unroll
            for (int r = 0; r < 4; ++r) c[mt][r] = 0.f;
    } else {
#pragma unroll
        for (int mt = 0; mt < 4; ++mt)
#pragma unroll
            for (int r = 0; r < 4; ++r) c[mt][r] = cbase[(mt * 4 + r) * 64];
    }

    floatx4 acc[4][4];                  // [M-tile][gate]
#pragma unroll
    for (int mt = 0; mt < 4; ++mt)
#pragma unroll
        for (int g = 0; g < 4; ++g) acc[mt][g] = (floatx4){0.f, 0.f, 0.f, 0.f};

    // A fragment: A[m = ln][k = qw*8 + jj], read straight from global (L2-hot)
    const _Float16* Abase = x_in + ((size_t)(ib * 256 + wv * 64 + ln)) * HID_ + qw * 8;
    const char* Bl = (const char*)Wl;
    const int lx = ln & 7;
    const int tE = (qw ^ lx) * 16;      // swizzled byte offset, kk-even

#pragma unroll
    for (int kk = 0; kk < 16; ++kk) {
        half8 a[4], b[4];
#pragma unroll
        for (int mt = 0; mt < 4; ++mt)
            a[mt] = *(const half8*)(Abase + mt * (16 * HID_) + kk * 32);
#pragma unroll
        for (int g = 0; g < 4; ++g) {
            int off = (g * 16 + ln) * 1024 + (kk >> 1) * 128 + (tE ^ ((kk & 1) << 6));
            b[g] = *(const half8*)(Bl + off);
        }
#pragma unroll
        for (int mt = 0; mt < 4; ++mt)
#pragma unroll
            for (int g = 0; g < 4; ++g)
                acc[mt][g] = __builtin_amdgcn_mfma_f32_16x16x32_f16(a[mt], b[g], acc[mt][g], 0, 0, 0);
    }

    // ---- epilogue: C/D layout col=ln, row=qw*4+r; all 4 gates in-thread ----
    _Float16* hbase = h_out + ((size_t)(ib * 256 + wv * 64 + qw * 4)) * HID_ + hid;
#pragma unroll
    for (int mt = 0; mt < 4; ++mt) {
#pragma unroll
        for (int r = 0; r < 4; ++r) {
            float gi = acc[mt][0][r] + bias[0];
            float gf = acc[mt][1][r] + bias[1];
            float gg = acc[mt][2][r] + bias[2];
            float go = acc[mt][3][r] + bias[3];
            float cn = sigf(gf) * c[mt][r] + sigf(gi) * tanhfast(gg);
            float hn = sigf(go) * tanhfast(cn);
            c[mt][r] = cn;
            hbase[(size_t)(mt * 16 + r) * HID_] = (_Float16)hn;
        }
    }
#pragma unroll
    for (int mt = 0; mt < 4; ++mt)
#pragma unroll
        for (int r = 0; r < 4; ++r) cbase[(mt * 4 + r) * 64] = c[mt][r];
}

// ---------------------------------------------------------------------------
// y[b,t,:] = hs[t][b,:] @ W_d^T + b_d. One wave per (b,t) row.
// ---------------------------------------------------------------------------
__global__ __launch_bounds__(256) void dense_kernel(
    const _Float16* __restrict__ hs, const float* __restrict__ Wd,
    const float* __restrict__ bd, float* __restrict__ y)
{
    int gw   = (blockIdx.x * 256 + threadIdx.x) >> 6;   // wave id [0, 65536)
    int lane = threadIdx.x & 63;
    int tt = gw & 31, b = gw >> 5;
    half8 h = *(const half8*)(hs + ((size_t)tt * BS_ + b) * HID_ + lane * 8);
    float s0 = 0.f, s1 = 0.f;
#pragma unroll
    for (int k = 0; k < 8; ++k) {
        float hv = (float)h[k];
        s0 += hv * Wd[lane * 8 + k];
        s1 += hv * Wd[HID_ + lane * 8 + k];
    }
#pragma unroll
    for (int m = 32; m >= 1; m >>= 1) {
        s0 += __shfl_xor(s0, m);
        s1 += __shfl_xor(s1, m);
    }
    if (lane == 0) {
        float* o = y + ((size_t)b * PH_ + tt) * 2;
        o[0] = s0 + bd[0];
        o[1] = s1 + bd[1];
    }
}

// ---------------------------------------------------------------------------
extern "C" void kernel_launch(void* const* d_in, const int* in_sizes, int n_in,
                              void* d_out, int out_size, void* d_ws, size_t ws_size,
                              hipStream_t stream)
{
    (void)in_sizes; (void)n_in; (void)out_size; (void)ws_size;
    // setup_inputs order: hist(0, unused), z(1), W_ih(2), W_hh(3), b_ih(4),
    //                     b_hh(5), W_d(6), b_d(7)
    const float* z   = (const float*)d_in[1];
    const float* Wih = (const float*)d_in[2];
    const float* Whh = (const float*)d_in[3];
    const float* bih = (const float*)d_in[4];
    const float* bhh = (const float*)d_in[5];
    const float* Wd  = (const float*)d_in[6];
    const float* bd  = (const float*)d_in[7];
    float* y = (float*)d_out;

    char* ws = (char*)d_ws;
    _Float16* hs     = (_Float16*)ws;                          // 32*2048*512*2 = 64 MB
    _Float16* z16    = (_Float16*)(ws + (size_t)67108864);     // 2 MB
    _Float16* wih16  = (_Float16*)(ws + (size_t)69206016);     // 2 MB
    _Float16* wsum16 = (_Float16*)(ws + (size_t)71303168);     // 2 MB
    float*    bsum   = (float*)   (ws + (size_t)73400320);     // 8 KB
    float*    c_ws   = (float*)   (ws + (size_t)73408512);     // 4 MB (end ~74 MB)

    prep_kernel<<<4096, 256, 0, stream>>>(Wih, Whh, bih, bhh, z, wih16, wsum16, z16, bsum);

    for (int t = 0; t < PH_; ++t) {
        const _Float16* xin = (t == 0) ? z16 : hs + (size_t)(t - 1) * BS_ * HID_;
        const _Float16* Wg  = (t == 0) ? wih16 : wsum16;
        lstm_step_kernel<<<256, 256, 0, stream>>>(Wg, bsum, xin,
                                                  hs + (size_t)t * BS_ * HID_, c_ws, t);
    }

    dense_kernel<<<16384, 256, 0, stream>>>(hs, Wd, bd, y);
}